// Round 5
// baseline (69.381 us; speedup 1.0000x reference)
//
#include <hip/hip_runtime.h>
#include <math.h>

#define N 8192
#define D 256
#define NCH 16                 // column chunks (grid.y)
#define RB 128                 // rows per block (4 waves x 32)
#define RT 2                   // row-tiles (16 rows) per wave
#define CHUNK (N / NCH)        // 512 cols per chunk
#define NCT (CHUNK / 16)       // 32 col-tiles of 16
#define NBUF 4                 // LDS pipeline depth

constexpr float MARGIN = 0.3f;
constexpr float EPS_PAIR = 1e-6f;
constexpr float BIAS = 512.0f;   // makes all scores positive -> asuint monotone

typedef float f32x4 __attribute__((ext_vector_type(4)));
typedef short s16x8 __attribute__((ext_vector_type(8)));
typedef short s16x4 __attribute__((ext_vector_type(4)));

// ---------- helpers ----------
__device__ __forceinline__ short bf16rne(float x) {
  unsigned u = __float_as_uint(x);
  unsigned r = (u + 0x7FFFu + ((u >> 16) & 1u)) >> 16;
  return (short)r;
}

__device__ __forceinline__ void load_lds16(const void* g, void* l) {
  __builtin_amdgcn_global_load_lds((const __attribute__((address_space(1))) void*)g,
                                   (__attribute__((address_space(3))) void*)l, 16, 0, 0);
}

// merge sorted pair (w1<=w2) into sorted running top-2 (v1<=v2), all packed u32
__device__ __forceinline__ void top2merge(unsigned& v1, unsigned& v2,
                                          unsigned w1, unsigned w2) {
  unsigned mx = v1 > w1 ? v1 : w1;
  v1 = v1 < w1 ? v1 : w1;
  unsigned mn = v2 < w2 ? v2 : w2;
  v2 = mx < mn ? mx : mn;
}

// ---------- kernel 0: fused bf16 convert + biased row squared norms ----------
__global__ void prep_kernel(const float* __restrict__ in, short* __restrict__ Abf,
                            float* __restrict__ sq512) {
  int row  = blockIdx.x * 4 + (threadIdx.x >> 6);
  int lane = threadIdx.x & 63;
  float4 v = ((const float4*)(in + (size_t)row * D))[lane];
  s16x4 b;
  b[0] = bf16rne(v.x); b[1] = bf16rne(v.y); b[2] = bf16rne(v.z); b[3] = bf16rne(v.w);
  *(s16x4*)(Abf + (size_t)row * D + lane * 4) = b;
  float s = v.x * v.x + v.y * v.y + v.z * v.z + v.w * v.w;
#pragma unroll
  for (int m = 32; m; m >>= 1) s += __shfl_xor(s, m);
  if (lane == 0) sq512[row] = s + BIAS;
}

// ---------- kernel 1: MFMA Gram + packed-u32 per-row top-2-min (per chunk) ----------
// Pipeline: 4-deep LDS ring, ONE raw barrier/iter, counted vmcnt(4) (never 0 in loop).
// Order per iter: vmcnt(4) [tile ct landed per-wave] -> s_barrier [all waves' parts
// landed; also WAR-protects buf (ct+3)&3, whose tile ct-1 was consumed by all waves
// before this barrier] -> stage(ct+3) -> ds_read/MFMA/select.
__global__ __launch_bounds__(256, 4) void neighbor_kernel(
    const short* __restrict__ Abf, const float* __restrict__ sq512,
    uint2* __restrict__ pp) {
  __shared__ __attribute__((aligned(16))) char ldsB[NBUF][8192];
  __shared__ float ldsSq[CHUNK];

  const int t = threadIdx.x;
  const int lane = t & 63;
  const int wave = t >> 6;
  const int rowBase = blockIdx.x * RB + wave * 32;   // this wave's 32 rows
  const int colBase = blockIdx.y * CHUNK;

  const int lrow = lane & 15;    // fragment row (A) / col (B) within 16-tile
  const int lkg  = lane >> 4;    // k-group 0..3

  // ---- A fragments: 2 row-tiles x 8 k-steps (64 VGPRs)
  s16x8 afrag[RT][8];
#pragma unroll
  for (int rt = 0; rt < RT; ++rt) {
    const short* arow = Abf + (size_t)(rowBase + rt * 16 + lrow) * D;
#pragma unroll
    for (int ks = 0; ks < 8; ++ks)
      afrag[rt][ks] = *(const s16x8*)(arow + ks * 32 + lkg * 8);
  }

  // ---- preload chunk's biased sq into LDS (keeps loop free of stray vmcnt ops)
#pragma unroll
  for (int i = t; i < CHUNK; i += 256) ldsSq[i] = sq512[colBase + i];

  // ---- packed running top-2 per (rt,q): score19 | idx13
  unsigned v1[RT][4], v2[RT][4];
#pragma unroll
  for (int rt = 0; rt < RT; ++rt)
#pragma unroll
    for (int q = 0; q < 4; ++q) { v1[rt][q] = 0xFFFFFFFFu; v2[rt][q] = 0xFFFFFFFFu; }

  // ---- stage col-tile ct: LDS linear dest, inverse-swizzled global src
  auto stage = [&](int buf, int ct) {
#pragma unroll
    for (int q = 0; q < 2; ++q) {
      int p = (wave * 2 + q) * 1024 + lane * 16;  // linear LDS byte position
      int r = p >> 9;                             // B row 0..15
      int o = p & 511;                            // within-row byte
      const char* src = (const char*)Abf +
          (size_t)(colBase + ct * 16 + r) * (D * 2) + (o ^ ((r & 7) << 4));
      load_lds16(src, &ldsB[buf][(wave * 2 + q) * 1024]);
    }
  };

  stage(0, 0);
  stage(1, 1);
  stage(2, 2);
  __syncthreads();   // prologue full drain (one-time)

  for (int ct = 0; ct < NCT; ++ct) {
    asm volatile("s_waitcnt vmcnt(4)" ::: "memory");  // tile ct landed; ct+1/ct+2 in flight
    __builtin_amdgcn_s_barrier();
    stage((ct + 3) & (NBUF - 1), (ct + 3) & (NCT - 1));  // wrap keeps count uniform

    const float sqjp = ldsSq[ct * 16 + lrow];  // sq[j] + BIAS

    const char* bt = ldsB[ct & (NBUF - 1)];
    f32x4 acc[RT];
#pragma unroll
    for (int rt = 0; rt < RT; ++rt) acc[rt] = (f32x4){0.f, 0.f, 0.f, 0.f};

#pragma unroll
    for (int ks = 0; ks < 8; ++ks) {
      int off = (ks * 64 + lkg * 16) ^ ((lrow & 7) << 4);   // swizzled read
      s16x8 bfrag = *(const s16x8*)(bt + lrow * 512 + off);
#pragma unroll
      for (int rt = 0; rt < RT; ++rt)
        acc[rt] = __builtin_amdgcn_mfma_f32_16x16x32_bf16(afrag[rt][ks], bfrag, acc[rt], 0, 0, 0);
    }

    const int j = colBase + ct * 16 + lrow;
#pragma unroll
    for (int rt = 0; rt < RT; ++rt) {
      const bool diag = (colBase + ct * 16) == (rowBase + rt * 16);  // wave-uniform
#pragma unroll
      for (int q = 0; q < 4; ++q) {
        float s = fmaf(-2.f, acc[rt][q], sqjp);       // dist^2 - sq[i] + BIAS > 0
        unsigned p = (__float_as_uint(s) & 0xFFFFE000u) | (unsigned)j;
        if (diag) p = (lrow == lkg * 4 + q) ? 0xFFFFFFFFu : p;  // exclude self
        unsigned mx = v1[rt][q] > p ? v1[rt][q] : p;
        v1[rt][q] = v1[rt][q] < p ? v1[rt][q] : p;
        v2[rt][q] = v2[rt][q] < mx ? v2[rt][q] : mx;
      }
    }
  }

  // ---- cross-lane merge over the 16 lanes sharing a row, write partials
#pragma unroll
  for (int rt = 0; rt < RT; ++rt) {
#pragma unroll
    for (int q = 0; q < 4; ++q) {
      unsigned a1 = v1[rt][q], a2 = v2[rt][q];
#pragma unroll
      for (int m = 1; m < 16; m <<= 1) {
        unsigned w1 = (unsigned)__shfl_xor((int)a1, m);
        unsigned w2 = (unsigned)__shfl_xor((int)a2, m);
        top2merge(a1, a2, w1, w2);
      }
      if (lrow == 0) {
        int ig = rowBase + rt * 16 + lkg * 4 + q;
        pp[(size_t)blockIdx.y * N + ig] = make_uint2(a1, a2);
      }
    }
  }
}

// ---------- kernel 2: fused chunk-merge + triplet hinge ----------
__global__ void finish_kernel(const float* __restrict__ A, const float* __restrict__ P,
                              const uint2* __restrict__ pp, float* __restrict__ rowLoss) {
  int row  = blockIdx.x * 4 + (threadIdx.x >> 6);
  int lane = threadIdx.x & 63;

  // merge the 16 chunk partials (lanes replicated x4, all compute same result)
  uint2 pr = pp[(size_t)(lane & 15) * N + row];
  unsigned a1 = pr.x, a2 = pr.y;
#pragma unroll
  for (int m = 1; m < 16; m <<= 1) {
    unsigned w1 = (unsigned)__shfl_xor((int)a1, m);
    unsigned w2 = (unsigned)__shfl_xor((int)a2, m);
    top2merge(a1, a2, w1, w2);
  }
  int nr = (int)(a2 & 0x1FFFu);   // 2nd-smallest among j != i == reference idx3[:,2]

  float4 av = ((const float4*)(A + (size_t)row * D))[lane];
  float4 pv = ((const float4*)(P + (size_t)row * D))[lane];
  float4 gv = ((const float4*)(A + (size_t)nr  * D))[lane];
  float dap = 0.f, dan = 0.f, x;
  x = av.x - pv.x + EPS_PAIR; dap += x * x;
  x = av.y - pv.y + EPS_PAIR; dap += x * x;
  x = av.z - pv.z + EPS_PAIR; dap += x * x;
  x = av.w - pv.w + EPS_PAIR; dap += x * x;
  x = av.x - gv.x + EPS_PAIR; dan += x * x;
  x = av.y - gv.y + EPS_PAIR; dan += x * x;
  x = av.z - gv.z + EPS_PAIR; dan += x * x;
  x = av.w - gv.w + EPS_PAIR; dan += x * x;
#pragma unroll
  for (int m = 32; m; m >>= 1) {
    dap += __shfl_xor(dap, m);
    dan += __shfl_xor(dan, m);
  }
  if (lane == 0)
    rowLoss[row] = fmaxf(sqrtf(dap) - sqrtf(dan) + MARGIN, 0.f);
}

// ---------- kernel 3: deterministic mean reduction ----------
__global__ void reduce_kernel(const float* __restrict__ rowLoss, float* __restrict__ out) {
  __shared__ float smem[256];
  int t = threadIdx.x;
  float s = 0.f;
  for (int i = t; i < N; i += 256) s += rowLoss[i];
  smem[t] = s;
  __syncthreads();
  for (int stride = 128; stride; stride >>= 1) {
    if (t < stride) smem[t] += smem[t + stride];
    __syncthreads();
  }
  if (t == 0) out[0] = smem[0] * (1.0f / (float)N);
}

// ---------- launch ----------
extern "C" void kernel_launch(void* const* d_in, const int* in_sizes, int n_in,
                              void* d_out, int out_size, void* d_ws, size_t ws_size,
                              hipStream_t stream) {
  const float* inputs   = (const float*)d_in[0];
  const float* positive = (const float*)d_in[1];
  float* out = (float*)d_out;

  // ws layout (~5.1 MB)
  short* Abf     = (short*)d_ws;                       // N*D bf16 (4 MB)
  float* sq512   = (float*)(Abf + (size_t)N * D);      // N
  uint2* pp      = (uint2*)(sq512 + N);                // NCH*N uint2 (1 MB)
  float* rowLoss = (float*)(pp + (size_t)NCH * N);     // N

  prep_kernel<<<N / 4, 256, 0, stream>>>(inputs, Abf, sq512);
  neighbor_kernel<<<dim3(N / RB, NCH), 256, 0, stream>>>(Abf, sq512, pp);
  finish_kernel<<<N / 4, 256, 0, stream>>>(inputs, positive, pp, rowLoss);
  reduce_kernel<<<1, 256, 0, stream>>>(rowLoss, out);
}

// Round 6
// 63.884 us; speedup vs baseline: 1.0860x; 1.0860x over previous
//
#include <hip/hip_runtime.h>
#include <math.h>

#define N 8192
#define D 256
#define NCH 16                 // column chunks (grid.y)
#define RB 256                 // rows per block (4 waves x 64)
#define RT 4                   // row-tiles (16 rows) per wave
#define CHUNK (N / NCH)        // 512 cols per chunk
#define NCT (CHUNK / 16)       // 32 col-tiles of 16
#define NBUF 2                 // LDS double buffer

constexpr float MARGIN = 0.3f;
constexpr float EPS_PAIR = 1e-6f;
constexpr float BIAS = 512.0f;

typedef float f32x4 __attribute__((ext_vector_type(4)));
typedef short s16x8 __attribute__((ext_vector_type(8)));
typedef short s16x4 __attribute__((ext_vector_type(4)));

// ---------- helpers ----------
__device__ __forceinline__ short bf16rne(float x) {
  unsigned u = __float_as_uint(x);
  unsigned r = (u + 0x7FFFu + ((u >> 16) & 1u)) >> 16;
  return (short)r;
}

__device__ __forceinline__ void load_lds16(const void* g, void* l) {
  __builtin_amdgcn_global_load_lds((const __attribute__((address_space(1))) void*)g,
                                   (__attribute__((address_space(3))) void*)l, 16, 0, 0);
}

// merge sorted pair (w1<=w2) into sorted running top-2 (v1<=v2), all packed u32
__device__ __forceinline__ void top2merge(unsigned& v1, unsigned& v2,
                                          unsigned w1, unsigned w2) {
  unsigned mx = v1 > w1 ? v1 : w1;
  v1 = v1 < w1 ? v1 : w1;
  unsigned mn = v2 < w2 ? v2 : w2;
  v2 = mx < mn ? mx : mn;
}

// ---------- kernel 0: fused bf16 convert + scaled row norms ----------
// sqh[i] = -0.5*(sq[i] + BIAS): used directly as the MFMA accumulator init so
// acc_final = G - (sq[j]+BIAS)/2 = -(score)/2 < 0; u32-min on the (negative)
// float bits ranks identically to ascending score.
__global__ void prep_kernel(const float* __restrict__ in, short* __restrict__ Abf,
                            float* __restrict__ sqh) {
  int row  = blockIdx.x * 4 + (threadIdx.x >> 6);
  int lane = threadIdx.x & 63;
  float4 v = ((const float4*)(in + (size_t)row * D))[lane];
  s16x4 b;
  b[0] = bf16rne(v.x); b[1] = bf16rne(v.y); b[2] = bf16rne(v.z); b[3] = bf16rne(v.w);
  *(s16x4*)(Abf + (size_t)row * D + lane * 4) = b;
  float s = v.x * v.x + v.y * v.y + v.z * v.z + v.w * v.w;
#pragma unroll
  for (int m = 32; m; m >>= 1) s += __shfl_xor(s, m);
  if (lane == 0) sqh[row] = -0.5f * (s + BIAS);
}

// ---------- kernel 1: MFMA Gram + packed-u32 per-row top-2-min (per chunk) ----------
__global__ __launch_bounds__(256, 2) void neighbor_kernel(
    const short* __restrict__ Abf, const float* __restrict__ sqh,
    uint2* __restrict__ pp) {
  __shared__ __attribute__((aligned(16))) char ldsB[NBUF][8192];
  __shared__ float ldsSq[CHUNK];

  const int t = threadIdx.x;
  const int lane = t & 63;
  const int wave = t >> 6;
  const int rowBase = blockIdx.x * RB + wave * 64;   // this wave's 64 rows
  const int colBase = blockIdx.y * CHUNK;

  const int lrow = lane & 15;    // fragment row (A) / col (B) within 16-tile
  const int lkg  = lane >> 4;    // k-group 0..3

  // ---- A fragments: 4 row-tiles x 8 k-steps (128 VGPRs, kernel-lifetime)
  s16x8 afrag[RT][8];
#pragma unroll
  for (int rt = 0; rt < RT; ++rt) {
    const short* arow = Abf + (size_t)(rowBase + rt * 16 + lrow) * D;
#pragma unroll
    for (int ks = 0; ks < 8; ++ks)
      afrag[rt][ks] = *(const s16x8*)(arow + ks * 32 + lkg * 8);
  }

  // ---- preload chunk's acc-init values into LDS
  for (int i = t; i < CHUNK; i += 256) ldsSq[i] = sqh[colBase + i];

  // ---- loop-invariant swizzled ds_read byte offsets (8 VGPRs)
  int dsoff[8];
#pragma unroll
  for (int ks = 0; ks < 8; ++ks)
    dsoff[ks] = lrow * 512 + ((ks * 64 + lkg * 16) ^ ((lrow & 7) << 4));

  // ---- stage src: two running per-lane pointers (inverse-swizzled), +8192/tile
  const int q0 = wave * 2, q1 = wave * 2 + 1;
  const char* src0;
  const char* src1;
  {
    int p0 = q0 * 1024 + lane * 16, p1 = q1 * 1024 + lane * 16;
    int r0 = p0 >> 9, r1 = p1 >> 9;
    int o0 = p0 & 511, o1 = p1 & 511;
    src0 = (const char*)Abf + (size_t)(colBase + r0) * 512 + (o0 ^ ((r0 & 7) << 4));
    src1 = (const char*)Abf + (size_t)(colBase + r1) * 512 + (o1 ^ ((r1 & 7) << 4));
  }

  // ---- packed running top-2 per (rt,q)
  unsigned v1[RT][4], v2[RT][4];
#pragma unroll
  for (int rt = 0; rt < RT; ++rt)
#pragma unroll
    for (int q = 0; q < 4; ++q) { v1[rt][q] = 0xFFFFFFFFu; v2[rt][q] = 0xFFFFFFFFu; }

  // prologue: stage tile 0 into buf 0
  load_lds16(src0, &ldsB[0][q0 * 1024]); src0 += 8192;
  load_lds16(src1, &ldsB[0][q1 * 1024]); src1 += 8192;
  __syncthreads();

  auto body = [&](int ct, int buf) {
    // stage next tile into the other buffer (latency hidden by this tile's MFMAs)
    if (ct + 1 < NCT) {
      load_lds16(src0, &ldsB[buf ^ 1][q0 * 1024]); src0 += 8192;
      load_lds16(src1, &ldsB[buf ^ 1][q1 * 1024]); src1 += 8192;
    }

    const float sqv = ldsSq[ct * 16 + lrow];   // -0.5*(sq[j]+BIAS)
    f32x4 acc[RT];
#pragma unroll
    for (int rt = 0; rt < RT; ++rt) acc[rt] = (f32x4){sqv, sqv, sqv, sqv};

    const char* bt = &ldsB[0][0] + buf * 8192;
#pragma unroll
    for (int ks = 0; ks < 8; ++ks) {
      s16x8 bfrag = *(const s16x8*)(bt + dsoff[ks]);
#pragma unroll
      for (int rt = 0; rt < RT; ++rt)
        acc[rt] = __builtin_amdgcn_mfma_f32_16x16x32_bf16(afrag[rt][ks], bfrag, acc[rt], 0, 0, 0);
    }

    const int j = colBase + ct * 16 + lrow;
#pragma unroll
    for (int rt = 0; rt < RT; ++rt) {
      const bool diag = (colBase + ct * 16) == (rowBase + rt * 16);  // wave-uniform
#pragma unroll
      for (int q = 0; q < 4; ++q) {
        // acc = -(score)/2, negative; more-negative (= worse) sorts higher as u32
        unsigned p = (__float_as_uint(acc[rt][q]) & 0xFFFFE000u) | (unsigned)j;
        if (diag) p = (lrow == lkg * 4 + q) ? 0xFFFFFFFFu : p;  // exclude self
        unsigned nv1 = v1[rt][q] < p ? v1[rt][q] : p;
        unsigned mx  = p > v1[rt][q] ? p : v1[rt][q];
        v2[rt][q] = v2[rt][q] < mx ? v2[rt][q] : mx;
        v1[rt][q] = nv1;
      }
    }
    __syncthreads();
  };

  for (int ct = 0; ct < NCT; ct += 2) {
    body(ct, 0);
    body(ct + 1, 1);
  }

  // ---- cross-lane merge over the 16 lanes sharing a row, write partials
#pragma unroll
  for (int rt = 0; rt < RT; ++rt) {
#pragma unroll
    for (int q = 0; q < 4; ++q) {
      unsigned a1 = v1[rt][q], a2 = v2[rt][q];
#pragma unroll
      for (int m = 1; m < 16; m <<= 1) {
        unsigned w1 = (unsigned)__shfl_xor((int)a1, m);
        unsigned w2 = (unsigned)__shfl_xor((int)a2, m);
        top2merge(a1, a2, w1, w2);
      }
      if (lrow == 0) {
        int ig = rowBase + rt * 16 + lkg * 4 + q;
        pp[(size_t)blockIdx.y * N + ig] = make_uint2(a1, a2);
      }
    }
  }
}

// ---------- kernel 2: fused chunk-merge + triplet hinge ----------
__global__ void finish_kernel(const float* __restrict__ A, const float* __restrict__ P,
                              const uint2* __restrict__ pp, float* __restrict__ rowLoss) {
  int row  = blockIdx.x * 4 + (threadIdx.x >> 6);
  int lane = threadIdx.x & 63;

  // merge the 16 chunk partials (lanes replicated x4, all compute same result)
  uint2 pr = pp[(size_t)(lane & 15) * N + row];
  unsigned a1 = pr.x, a2 = pr.y;
#pragma unroll
  for (int m = 1; m < 16; m <<= 1) {
    unsigned w1 = (unsigned)__shfl_xor((int)a1, m);
    unsigned w2 = (unsigned)__shfl_xor((int)a2, m);
    top2merge(a1, a2, w1, w2);
  }
  int nr = (int)(a2 & 0x1FFFu);   // 2nd-smallest among j != i == reference idx3[:,2]

  float4 av = ((const float4*)(A + (size_t)row * D))[lane];
  float4 pv = ((const float4*)(P + (size_t)row * D))[lane];
  float4 gv = ((const float4*)(A + (size_t)nr  * D))[lane];
  float dap = 0.f, dan = 0.f, x;
  x = av.x - pv.x + EPS_PAIR; dap += x * x;
  x = av.y - pv.y + EPS_PAIR; dap += x * x;
  x = av.z - pv.z + EPS_PAIR; dap += x * x;
  x = av.w - pv.w + EPS_PAIR; dap += x * x;
  x = av.x - gv.x + EPS_PAIR; dan += x * x;
  x = av.y - gv.y + EPS_PAIR; dan += x * x;
  x = av.z - gv.z + EPS_PAIR; dan += x * x;
  x = av.w - gv.w + EPS_PAIR; dan += x * x;
#pragma unroll
  for (int m = 32; m; m >>= 1) {
    dap += __shfl_xor(dap, m);
    dan += __shfl_xor(dan, m);
  }
  if (lane == 0)
    rowLoss[row] = fmaxf(sqrtf(dap) - sqrtf(dan) + MARGIN, 0.f);
}

// ---------- kernel 3: deterministic mean reduction ----------
__global__ void reduce_kernel(const float* __restrict__ rowLoss, float* __restrict__ out) {
  __shared__ float smem[256];
  int t = threadIdx.x;
  float s = 0.f;
  for (int i = t; i < N; i += 256) s += rowLoss[i];
  smem[t] = s;
  __syncthreads();
  for (int stride = 128; stride; stride >>= 1) {
    if (t < stride) smem[t] += smem[t + stride];
    __syncthreads();
  }
  if (t == 0) out[0] = smem[0] * (1.0f / (float)N);
}

// ---------- launch ----------
extern "C" void kernel_launch(void* const* d_in, const int* in_sizes, int n_in,
                              void* d_out, int out_size, void* d_ws, size_t ws_size,
                              hipStream_t stream) {
  const float* inputs   = (const float*)d_in[0];
  const float* positive = (const float*)d_in[1];
  float* out = (float*)d_out;

  // ws layout (~5.1 MB)
  short* Abf     = (short*)d_ws;                       // N*D bf16 (4 MB)
  float* sqh     = (float*)(Abf + (size_t)N * D);      // N
  uint2* pp      = (uint2*)(sqh + N);                  // NCH*N uint2 (1 MB)
  float* rowLoss = (float*)(pp + (size_t)NCH * N);     // N

  prep_kernel<<<N / 4, 256, 0, stream>>>(inputs, Abf, sqh);
  neighbor_kernel<<<dim3(N / RB, NCH), 256, 0, stream>>>(Abf, sqh, pp);
  finish_kernel<<<N / 4, 256, 0, stream>>>(inputs, positive, pp, rowLoss);
  reduce_kernel<<<1, 256, 0, stream>>>(rowLoss, out);
}